// Round 6
// baseline (437.945 us; speedup 1.0000x reference)
//
#include <hip/hip_runtime.h>
#include <hip/hip_bf16.h>

typedef unsigned short u16;
typedef unsigned int   u32;

#define N_NODES 50000
#define N_EDGES 500000
#define IN_DIM  512
#define HID     256
#define OUT_DIM 64

typedef __bf16 bf16x8 __attribute__((ext_vector_type(8)));
typedef float  f32x4  __attribute__((ext_vector_type(4)));

#define GLOBAL_AS __attribute__((address_space(1)))
#define LDS_AS    __attribute__((address_space(3)))

__device__ __forceinline__ float bf2f(u16 u) {
  union { u32 i; float f; } x; x.i = ((u32)u) << 16; return x.f;
}
__device__ __forceinline__ u16 f2bf(float f) {
  union { float f; u32 i; } x; x.f = f;
  u32 r = x.i + 0x7FFFu + ((x.i >> 16) & 1u);
  return (u16)(r >> 16);
}
__device__ __forceinline__ u32 pkbf(float a, float b) {
  return (u32)f2bf(a) | ((u32)f2bf(b) << 16);
}
__device__ __forceinline__ float lo2f(u32 w) {
  union { u32 i; float f; } x; x.i = w << 16; return x.f;
}
__device__ __forceinline__ float hi2f(u32 w) {
  union { u32 i; float f; } x; x.i = w & 0xFFFF0000u; return x.f;
}

// ---------------- dtype detector (validated R2/R3) ----------------
__global__ void detect_dtype(const u32* __restrict__ feat, int* __restrict__ flag) {
  __shared__ int s[256];
  int t = threadIdx.x;
  int hits = 0;
  for (int i = t; i < 1024; i += 256) {
    u32 e = (feat[i] >> 7) & 0xFF;
    hits += (e >= 100 && e <= 140) ? 1 : 0;
  }
  s[t] = hits;
  __syncthreads();
  for (int o = 128; o > 0; o >>= 1) {
    if (t < o) s[t] += s[t + o];
    __syncthreads();
  }
  if (t == 0) *flag = (s[0] > 716) ? 1 : 0;  // 1 = bf16, 0 = f32
}

// ---------------- one-shot weight/attn prep: convert + transposes ----------
__global__ void prep(const void* __restrict__ W1r, const void* __restrict__ W2r,
                     const void* __restrict__ atsr, const void* __restrict__ atdr,
                     u16* __restrict__ W1b, u16* __restrict__ W2b,
                     u16* __restrict__ attsb, u16* __restrict__ attdb,
                     u16* __restrict__ W1T, u16* __restrict__ W2T,
                     const int* __restrict__ flag) {
  const int fv = *flag;
  int i = blockIdx.x * 256 + threadIdx.x;
  int stride = gridDim.x * 256;
  const int NW1 = HID * IN_DIM;   // 131072
  const int NW2 = OUT_DIM * HID;  // 16384
  for (int j = i; j < NW1; j += stride) {
    u16 v = fv ? ((const u16*)W1r)[j] : f2bf(((const float*)W1r)[j]);
    W1b[j] = v;
    int r = j >> 9, c = j & 511;        // j / IN_DIM, j % IN_DIM
    W1T[c * HID + r] = v;
  }
  for (int j = i; j < NW2; j += stride) {
    u16 v = fv ? ((const u16*)W2r)[j] : f2bf(((const float*)W2r)[j]);
    W2b[j] = v;
    int r = j >> 8, c = j & 255;        // j / HID, j % HID
    W2T[c * OUT_DIM + r] = v;
  }
  if (blockIdx.x == 0 && threadIdx.x < HID) {
    int t = threadIdx.x;
    attsb[t] = fv ? ((const u16*)atsr)[t] : f2bf(((const float*)atsr)[t]);
    attdb[t] = fv ? ((const u16*)atdr)[t] : f2bf(((const float*)atdr)[t]);
  }
}

// ---------------- async 16B global->LDS ----------------
__device__ __forceinline__ void glds16(const u16* g, __bf16* l) {
  __builtin_amdgcn_global_load_lds((const GLOBAL_AS u32*)g, (LDS_AS u32*)l, 16, 0, 0);
}

// ---------------- NT GEMM: C[M,N]=A[M,K]*B[N,K]^T ----------------
// 64x128 tile, BK=64, 4 waves (2Mx2N), 16 MFMA/wave/iter.
// R6: catalog T3 minimal 2-phase with DOUBLE-BUFFERED LDS (As[2]/Bs[2],
// 48KB, 3 blocks/CU). Per iter tail (post-MFMA): [cvt+ds_write A(t+1)] ->
// vmcnt(0)+lgkmcnt(0) -> s_barrier -> issue stage(t+2) into buf[t&1].
// Every staging load has the full next MFMA phase to land -> vmcnt(0) free.
// Hazards: buf[t&1] rewritten only after the barrier following MFMA(t)
// (ds_reads all consumed pre-barrier); A-write hits buf[(t+1)&1], last read
// at MFMA(t-1), separated by the t-1 barrier. One barrier/iter, full drain.
// LDS layout: row-major [row][64] bf16 with 16B-segment XOR swizzle
// (phys_seg = seg ^ (row&7)); glds16 pre-swizzles the GLOBAL address
// (m173/G21), reg path swizzles the ds_write address. Reads apply same XOR.
// ABF16=1: A+B staged via global_load_lds (bf16 input).
// ABF16=0: A is f32, reg-staged + converted; B via glds16.
// MODE 1: final out (f32/bf16 per *flag) at outbase+out_off
// MODE 2: bf16 -> Cb with fused ELU
// MODE 3: bf16 -> Cb + fused attention dots (atomicAdd partials to a_s/a_d)
template <int MODE, int ABF16>
__global__ __launch_bounds__(256) void gemm128(const u16* __restrict__ A,
                                               const float* __restrict__ Af32,
                                               const u16* __restrict__ B,
                                               u16* __restrict__ Cb,
                                               void* __restrict__ outbase,
                                               size_t out_off,
                                               const u16* __restrict__ attsb,
                                               const u16* __restrict__ attdb,
                                               float* __restrict__ a_s,
                                               float* __restrict__ a_d,
                                               const int* __restrict__ flag,
                                               int M, int N, int K) {
  __shared__ __bf16 As[2][64 * 64];
  __shared__ __bf16 Bs[2][128 * 64];
  __shared__ float as_l[128];
  __shared__ float ad_l[128];

  const int fv = *flag;
  if (MODE == 3 && ABF16 != fv) return;  // dtype-specialized variant gate

  const int tid  = threadIdx.x;
  const int wave = tid >> 6;
  const int lane = tid & 63;
  const int m0   = blockIdx.x * 64;
  const int n0   = blockIdx.y * 128;
  const int wm   = (wave >> 1) * 32;
  const int wn   = (wave & 1) * 64;
  const int quad = lane >> 4;
  const int l16  = lane & 15;

  if (MODE == 3 && tid < 128) {
    as_l[tid] = bf2f(attsb[n0 + tid]);
    ad_l[tid] = bf2f(attdb[n0 + tid]);
  }

  // staging geometry: per glds16 round a wave covers 8 rows x 8 segs of 16B
  const int r8 = lane >> 3;        // row within 8-row group
  const int sg = (lane & 7) ^ r8;  // pre-swizzled global 16B segment

  const u16* bp[4];
#pragma unroll
  for (int l = 0; l < 4; ++l) {
    int br = n0 + l * 32 + wave * 8 + r8;  // N is a multiple of 128
    bp[l] = B + (size_t)br * K + sg * 8;
  }

  const u16* ap[2];
  if (ABF16) {
#pragma unroll
    for (int l = 0; l < 2; ++l) {
      int ar = m0 + l * 32 + wave * 8 + r8;
      if (ar >= M) ar = M - 1;
      ap[l] = A + (size_t)ar * K + sg * 8;
    }
  }
  // f32 reg-stage path: thread t -> row t>>2, quarter t&3 (16 floats)
  const float* afp = nullptr;
  const int rr = tid >> 2, hh = tid & 3;
  if (!ABF16) {
    int ar = m0 + rr;
    if (ar >= M) ar = M - 1;
    afp = Af32 + (size_t)ar * K + hh * 16;
  }

  f32x4 acc[2][4];
#pragma unroll
  for (int i = 0; i < 2; ++i)
#pragma unroll
    for (int j = 0; j < 4; ++j) acc[i][j] = (f32x4)0.f;

  const int nt = K >> 6;  // K / 64
  float4 fa[4];

  // ---- prologue: stage tile 0 into buf0 ----
  if (ABF16) {
#pragma unroll
    for (int l = 0; l < 2; ++l)
      glds16(ap[l], As[0] + (l * 32 + wave * 8) * 64);
  }
#pragma unroll
  for (int l = 0; l < 4; ++l)
    glds16(bp[l], Bs[0] + (l * 32 + wave * 8) * 64);
  if (!ABF16) {
#pragma unroll
    for (int c = 0; c < 4; ++c) fa[c] = *(const float4*)(afp + 4 * c);
#pragma unroll
    for (int j = 0; j < 2; ++j) {
      int phys = ((hh * 2 + j) ^ (rr & 7)) * 8;
      uint4 o;
      o.x = pkbf(fa[2 * j].x, fa[2 * j].y);
      o.y = pkbf(fa[2 * j].z, fa[2 * j].w);
      o.z = pkbf(fa[2 * j + 1].x, fa[2 * j + 1].y);
      o.w = pkbf(fa[2 * j + 1].z, fa[2 * j + 1].w);
      *(uint4*)&As[0][rr * 64 + phys] = o;
    }
  }
  asm volatile("s_waitcnt vmcnt(0) lgkmcnt(0)" ::: "memory");
  __builtin_amdgcn_s_barrier();
  // ---- stage tile 1 into buf1 (stays in flight across MFMA(0)) ----
  if (nt > 1) {
    if (ABF16) {
#pragma unroll
      for (int l = 0; l < 2; ++l)
        glds16(ap[l] + 64, As[1] + (l * 32 + wave * 8) * 64);
    }
#pragma unroll
    for (int l = 0; l < 4; ++l)
      glds16(bp[l] + 64, Bs[1] + (l * 32 + wave * 8) * 64);
    if (!ABF16) {
#pragma unroll
      for (int c = 0; c < 4; ++c) fa[c] = *(const float4*)(afp + 64 + 4 * c);
    }
  }

  for (int t = 0; t < nt; ++t) {
    const __bf16* Asb = As[t & 1];
    const __bf16* Bsb = Bs[t & 1];

    bf16x8 af[2][2], bfr[4][2];
#pragma unroll
    for (int ks = 0; ks < 2; ++ks) {
#pragma unroll
      for (int mi = 0; mi < 2; ++mi)
        af[mi][ks] = *(const bf16x8*)&Asb[(wm + mi * 16 + l16) * 64 +
                                          (((ks * 4 + quad) ^ (l16 & 7)) * 8)];
#pragma unroll
      for (int ni = 0; ni < 4; ++ni)
        bfr[ni][ks] = *(const bf16x8*)&Bsb[(wn + ni * 16 + l16) * 64 +
                                           (((ks * 4 + quad) ^ (l16 & 7)) * 8)];
    }
#pragma unroll
    for (int ks = 0; ks < 2; ++ks)
#pragma unroll
      for (int mi = 0; mi < 2; ++mi)
#pragma unroll
        for (int ni = 0; ni < 4; ++ni)
          acc[mi][ni] = __builtin_amdgcn_mfma_f32_16x16x32_bf16(
              af[mi][ks], bfr[ni][ks], acc[mi][ni], 0, 0, 0);

    if (t + 1 < nt) {
      if (!ABF16) {
        // convert regs A(t+1) -> ds_write As[(t+1)&1] (compiler waits fa)
#pragma unroll
        for (int j = 0; j < 2; ++j) {
          int phys = ((hh * 2 + j) ^ (rr & 7)) * 8;
          uint4 o;
          o.x = pkbf(fa[2 * j].x, fa[2 * j].y);
          o.y = pkbf(fa[2 * j].z, fa[2 * j].w);
          o.z = pkbf(fa[2 * j + 1].x, fa[2 * j + 1].y);
          o.w = pkbf(fa[2 * j + 1].z, fa[2 * j + 1].w);
          *(uint4*)&As[(t + 1) & 1][rr * 64 + phys] = o;
        }
      }
      // stage(t+1) had the whole MFMA(t) to land -> this drain is cheap
      asm volatile("s_waitcnt vmcnt(0) lgkmcnt(0)" ::: "memory");
      __builtin_amdgcn_s_barrier();
      if (t + 2 < nt) {
        const size_t ko = (size_t)(t + 2) * 64;
        if (ABF16) {
#pragma unroll
          for (int l = 0; l < 2; ++l)
            glds16(ap[l] + ko, As[t & 1] + (l * 32 + wave * 8) * 64);
        }
#pragma unroll
        for (int l = 0; l < 4; ++l)
          glds16(bp[l] + ko, Bs[t & 1] + (l * 32 + wave * 8) * 64);
        if (!ABF16) {
#pragma unroll
          for (int c = 0; c < 4; ++c)
            fa[c] = *(const float4*)(afp + ko + 4 * c);
        }
      }
    }
  }

  if (MODE == 3) {
    __syncthreads();  // as_l/ad_l visible (loaded pre-loop, barrier-covered anyway)
#pragma unroll
    for (int mi = 0; mi < 2; ++mi)
#pragma unroll
      for (int r = 0; r < 4; ++r) {
        float ps = 0.f, pd = 0.f;
#pragma unroll
        for (int ni = 0; ni < 4; ++ni) {
          int c = wn + ni * 16 + l16;
          ps += acc[mi][ni][r] * as_l[c];
          pd += acc[mi][ni][r] * ad_l[c];
        }
#pragma unroll
        for (int o = 1; o < 16; o <<= 1) {
          ps += __shfl_xor(ps, o);
          pd += __shfl_xor(pd, o);
        }
        int gr = m0 + wm + mi * 16 + quad * 4 + r;
        if (l16 == 0 && gr < M) {
          atomicAdd(&a_s[gr], ps);
          atomicAdd(&a_d[gr], pd);
        }
      }
  }

#pragma unroll
  for (int mi = 0; mi < 2; ++mi)
#pragma unroll
    for (int ni = 0; ni < 4; ++ni)
#pragma unroll
      for (int r = 0; r < 4; ++r) {
        int gr = m0 + wm + mi * 16 + quad * 4 + r;  // row = quad*4+reg (m89)
        int gc = n0 + wn + ni * 16 + l16;           // col = lane&15
        if (gr < M) {
          float  v   = acc[mi][ni][r];
          size_t idx = (size_t)gr * N + gc;
          if (MODE == 1) {
            if (fv) ((u16*)outbase)[out_off + idx] = f2bf(v);
            else    ((float*)outbase)[out_off + idx] = v;
          } else if (MODE == 2) {
            v = (v > 0.f) ? v : expm1f(v);
            Cb[idx] = f2bf(v);
          } else {
            Cb[idx] = f2bf(v);
          }
        }
      }
}

// ---------------- 64-tile NT GEMM for N=64 (h2): dual out + bf16 copy -----
__global__ __launch_bounds__(256) void gemm_h2(const u16* __restrict__ A,
                                               const u16* __restrict__ B,
                                               void* __restrict__ outbase,
                                               u16* __restrict__ Cb,
                                               const int* __restrict__ flag,
                                               int M, int N, int K) {
  __shared__ __bf16 As[64 * 48];
  __shared__ __bf16 Bs[64 * 48];

  const int tid  = threadIdx.x;
  const int m0   = blockIdx.x * 64;
  const int wave = tid >> 6;
  const int lane = tid & 63;
  const int wm   = (wave >> 1) * 32;
  const int wn   = (wave & 1) * 32;
  const int quad = lane >> 4;
  const int l16  = lane & 15;

  const int srow = tid >> 2;
  const int sseg = (tid & 3) * 8;
  int arow = m0 + srow;
  if (arow >= M) arow = M - 1;
  const size_t a_base = (size_t)arow * K + sseg;
  const size_t b_base = (size_t)srow * K + sseg;  // n0 = 0 (N=64)

  f32x4 acc[2][2];
#pragma unroll
  for (int i = 0; i < 2; ++i)
#pragma unroll
    for (int j = 0; j < 2; ++j) acc[i][j] = (f32x4)0.f;

  for (int k0 = 0; k0 < K; k0 += 32) {
    uint4 av = *(const uint4*)(A + a_base + k0);
    uint4 bv = *(const uint4*)(B + b_base + k0);
    __syncthreads();
    *(uint4*)(&As[srow * 48 + sseg]) = av;
    *(uint4*)(&Bs[srow * 48 + sseg]) = bv;
    __syncthreads();

    bf16x8 af[2], bfr[2];
#pragma unroll
    for (int mi = 0; mi < 2; ++mi)
      af[mi] = *(const bf16x8*)(&As[(wm + mi * 16 + l16) * 48 + quad * 8]);
#pragma unroll
    for (int ni = 0; ni < 2; ++ni)
      bfr[ni] = *(const bf16x8*)(&Bs[(wn + ni * 16 + l16) * 48 + quad * 8]);
#pragma unroll
    for (int mi = 0; mi < 2; ++mi)
#pragma unroll
      for (int ni = 0; ni < 2; ++ni)
        acc[mi][ni] = __builtin_amdgcn_mfma_f32_16x16x32_bf16(
            af[mi], bfr[ni], acc[mi][ni], 0, 0, 0);
  }

  const int fv = *flag;
#pragma unroll
  for (int mi = 0; mi < 2; ++mi)
#pragma unroll
    for (int ni = 0; ni < 2; ++ni)
#pragma unroll
      for (int r = 0; r < 4; ++r) {
        int gr = m0 + wm + mi * 16 + quad * 4 + r;
        int gc = wn + ni * 16 + l16;
        if (gr < M && gc < N) {
          float  v   = acc[mi][ni][r];
          size_t idx = (size_t)gr * N + gc;
          u16 bv = f2bf(v);
          if (fv) ((u16*)outbase)[idx] = bv;
          else    ((float*)outbase)[idx] = v;
          Cb[idx] = bv;
        }
      }
}

// ---------------- CSR build ----------------
__global__ void hist_kernel(const int* __restrict__ dst, int* __restrict__ counts) {
  int e = blockIdx.x * 256 + threadIdx.x;
  if (e < N_EDGES) atomicAdd(&counts[dst[e]], 1);
}

__global__ void block_sum(const int* __restrict__ counts, int n,
                          int* __restrict__ bsums) {
  __shared__ int s[256];
  int i = blockIdx.x * 256 + threadIdx.x;
  s[threadIdx.x] = (i < n) ? counts[i] : 0;
  __syncthreads();
  for (int off = 128; off > 0; off >>= 1) {
    if (threadIdx.x < off) s[threadIdx.x] += s[threadIdx.x + off];
    __syncthreads();
  }
  if (threadIdx.x == 0) bsums[blockIdx.x] = s[0];
}

__global__ void scan_bsums(const int* __restrict__ bsums, int nb,
                           int* __restrict__ boffs) {
  __shared__ int s[256];
  int t = threadIdx.x;
  int v = (t < nb) ? bsums[t] : 0;
  s[t] = v;
  __syncthreads();
  for (int off = 1; off < 256; off <<= 1) {
    int add = (t >= off) ? s[t - off] : 0;
    __syncthreads();
    s[t] += add;
    __syncthreads();
  }
  boffs[t] = s[t] - v;  // exclusive
}

__global__ void scan_final(const int* __restrict__ counts,
                           const int* __restrict__ boffs, int n,
                           int* __restrict__ offsets, int* __restrict__ cursor) {
  __shared__ int s[256];
  int t = threadIdx.x;
  int i = blockIdx.x * 256 + t;
  int v = (i < n) ? counts[i] : 0;
  s[t] = v;
  __syncthreads();
  for (int off = 1; off < 256; off <<= 1) {
    int add = (t >= off) ? s[t - off] : 0;
    __syncthreads();
    s[t] += add;
    __syncthreads();
  }
  int excl = boffs[blockIdx.x] + s[t] - v;
  if (i < n) {
    offsets[i] = excl;
    cursor[i]  = excl;
  }
  if (i == n - 1) offsets[n] = excl + v;
}

// sigmoid in (0,1) -> exp never overflows; segment-max cancels in softmax.
__global__ void edge_scatter(const int* __restrict__ src, const int* __restrict__ dst,
                             const float* __restrict__ a_s, const float* __restrict__ a_d,
                             float* __restrict__ denom, int* __restrict__ cursor,
                             int2* __restrict__ edges) {
  int e = blockIdx.x * 256 + threadIdx.x;
  if (e >= N_EDGES) return;
  int s = src[e], d = dst[e];
  float x  = a_s[s] + a_d[d];
  float a  = 1.f / (1.f + expf(-x));
  float ev = expf(a);
  atomicAdd(&denom[d], ev);
  int pos = atomicAdd(&cursor[d], 1);
  edges[pos] = make_int2(s, __float_as_int(ev));
}

// ---------------- prop 256-dim: 32-lane subgroup/node, fused ELU ----------
// Edge loop unrolled x2: two (edge, row) load pairs in flight per iteration
// (hipcc otherwise drains vmcnt before each row use -> 1 gather in flight).
__global__ __launch_bounds__(256) void prop256(
    const int* __restrict__ offs, const int2* __restrict__ edges,
    const float* __restrict__ denom, const u16* __restrict__ feat,
    u16* __restrict__ out) {
  const int sub  = threadIdx.x >> 5;
  const int lane = threadIdx.x & 31;
  const int nd   = blockIdx.x * 8 + sub;
  const int col  = lane * 8;
  const int beg = offs[nd], end = offs[nd + 1];
  float a[8];
#pragma unroll
  for (int j = 0; j < 8; ++j) a[j] = 0.f;
  int e = beg;
  for (; e + 1 < end; e += 2) {
    int2  e0 = edges[e];
    int2  e1 = edges[e + 1];
    float v0 = __int_as_float(e0.y);
    float v1 = __int_as_float(e1.y);
    uint4 w0 = *(const uint4*)(feat + (size_t)e0.x * HID + col);
    uint4 w1 = *(const uint4*)(feat + (size_t)e1.x * HID + col);
    a[0] += v0 * lo2f(w0.x); a[1] += v0 * hi2f(w0.x);
    a[2] += v0 * lo2f(w0.y); a[3] += v0 * hi2f(w0.y);
    a[4] += v0 * lo2f(w0.z); a[5] += v0 * hi2f(w0.z);
    a[6] += v0 * lo2f(w0.w); a[7] += v0 * hi2f(w0.w);
    a[0] += v1 * lo2f(w1.x); a[1] += v1 * hi2f(w1.x);
    a[2] += v1 * lo2f(w1.y); a[3] += v1 * hi2f(w1.y);
    a[4] += v1 * lo2f(w1.z); a[5] += v1 * hi2f(w1.z);
    a[6] += v1 * lo2f(w1.w); a[7] += v1 * hi2f(w1.w);
  }
  if (e < end) {
    int2  ed = edges[e];
    float ev = __int_as_float(ed.y);
    uint4 w = *(const uint4*)(feat + (size_t)ed.x * HID + col);
    a[0] += ev * lo2f(w.x); a[1] += ev * hi2f(w.x);
    a[2] += ev * lo2f(w.y); a[3] += ev * hi2f(w.y);
    a[4] += ev * lo2f(w.z); a[5] += ev * hi2f(w.z);
    a[6] += ev * lo2f(w.w); a[7] += ev * hi2f(w.w);
  }
  float dn = 1.f / (denom[nd] + 1e-16f);
  u32 p[4];
#pragma unroll
  for (int j = 0; j < 4; ++j) {
    float r0 = a[2 * j] * dn;
    float r1 = a[2 * j + 1] * dn;
    r0 = (r0 > 0.f) ? r0 : expm1f(r0);
    r1 = (r1 > 0.f) ? r1 : expm1f(r1);
    p[j] = (u32)f2bf(r0) | ((u32)f2bf(r1) << 16);
  }
  *(uint4*)(out + (size_t)nd * HID + col) = make_uint4(p[0], p[1], p[2], p[3]);
}

// ---------------- prop 64-dim (on h2): 8-lane subgroup/node, no ELU -------
__global__ __launch_bounds__(256) void prop64(
    const int* __restrict__ offs, const int2* __restrict__ edges,
    const float* __restrict__ denom, const u16* __restrict__ feat,
    u16* __restrict__ out) {
  const int sub  = threadIdx.x >> 3;
  const int lane = threadIdx.x & 7;
  const int nd   = blockIdx.x * 32 + sub;
  if (nd >= N_NODES) return;
  const int col  = lane * 8;
  const int beg = offs[nd], end = offs[nd + 1];
  float a[8];
#pragma unroll
  for (int j = 0; j < 8; ++j) a[j] = 0.f;
  int e = beg;
  for (; e + 1 < end; e += 2) {
    int2  e0 = edges[e];
    int2  e1 = edges[e + 1];
    float v0 = __int_as_float(e0.y);
    float v1 = __int_as_float(e1.y);
    uint4 w0 = *(const uint4*)(feat + (size_t)e0.x * OUT_DIM + col);
    uint4 w1 = *(const uint4*)(feat + (size_t)e1.x * OUT_DIM + col);
    a[0] += v0 * lo2f(w0.x); a[1] += v0 * hi2f(w0.x);
    a[2] += v0 * lo2f(w0.y); a[3] += v0 * hi2f(w0.y);
    a[4] += v0 * lo2f(w0.z); a[5] += v0 * hi2f(w0.z);
    a[6] += v0 * lo2f(w0.w); a[7] += v0 * hi2f(w0.w);
    a[0] += v1 * lo2f(w1.x); a[1] += v1 * hi2f(w1.x);
    a[2] += v1 * lo2f(w1.y); a[3] += v1 * hi2f(w1.y);
    a[4] += v1 * lo2f(w1.z); a[5] += v1 * hi2f(w1.z);
    a[6] += v1 * lo2f(w1.w); a[7] += v1 * hi2f(w1.w);
  }
  if (e < end) {
    int2  ed = edges[e];
    float ev = __int_as_float(ed.y);
    uint4 w = *(const uint4*)(feat + (size_t)ed.x * OUT_DIM + col);
    a[0] += ev * lo2f(w.x); a[1] += ev * hi2f(w.x);
    a[2] += ev * lo2f(w.y); a[3] += ev * hi2f(w.y);
    a[4] += ev * lo2f(w.z); a[5] += ev * hi2f(w.z);
    a[6] += ev * lo2f(w.w); a[7] += ev * hi2f(w.w);
  }
  float dn = 1.f / (denom[nd] + 1e-16f);
  u32 p[4];
#pragma unroll
  for (int j = 0; j < 4; ++j) {
    p[j] = (u32)f2bf(a[2 * j] * dn) | ((u32)f2bf(a[2 * j + 1] * dn) << 16);
  }
  *(uint4*)(out + (size_t)nd * OUT_DIM + col) = make_uint4(p[0], p[1], p[2], p[3]);
}

// ---------------- launch ----------------
extern "C" void kernel_launch(void* const* d_in, const int* in_sizes, int n_in,
                              void* d_out, int out_size, void* d_ws, size_t ws_size,
                              hipStream_t stream) {
  const void* X    = d_in[0];
  const void* W1   = d_in[1];
  const void* W2   = d_in[2];
  const void* atts = d_in[3];
  const void* attd = d_in[4];
  const int*  eidx = (const int*)d_in[5];
  const int*  esrc = eidx;
  const int*  edst = eidx + N_EDGES;

  char*  ws  = (char*)d_ws;
  size_t off = 0;
  auto alloc = [&](size_t bytes) -> void* {
    void* p = ws + off;
    off += (bytes + 255) & ~(size_t)255;
    return p;
  };
  u16*   W1b    = (u16*)alloc((size_t)HID * IN_DIM * 2);
  u16*   W2b    = (u16*)alloc((size_t)OUT_DIM * HID * 2);
  u16*   attsb  = (u16*)alloc(HID * 2);
  u16*   attdb  = (u16*)alloc(HID * 2);
  u16*   W1T    = (u16*)alloc((size_t)IN_DIM * HID * 2);
  u16*   W2T    = (u16*)alloc((size_t)HID * OUT_DIM * 2);
  u16*   feat   = (u16*)alloc((size_t)N_NODES * HID * 2);   // h1p, later h3
  u16*   h1     = (u16*)alloc((size_t)N_NODES * HID * 2);
  u16*   h2b    = (u16*)alloc((size_t)N_NODES * OUT_DIM * 2);
  u16*   ph2    = (u16*)alloc((size_t)N_NODES * OUT_DIM * 2);
  float* a_s    = (float*)alloc(N_NODES * 4);   // zero region start
  float* a_d    = (float*)alloc(N_NODES * 4);
  float* denom  = (float*)alloc(N_NODES * 4);
  int*   counts = (int*)alloc(N_NODES * 4);     // zero region end
  int*   offsets= (int*)alloc((N_NODES + 1) * 4);
  int*   cursor = (int*)alloc(N_NODES * 4);
  int*   bsums  = (int*)alloc(1024 * 4);
  int*   boffs  = (int*)alloc(1024 * 4);
  int2*  edges  = (int2*)alloc((size_t)N_EDGES * 8);
  int*   flag   = (int*)alloc(256);
  (void)ws_size; (void)in_sizes; (void)n_in; (void)out_size;

  size_t zero_bytes = (size_t)((char*)offsets - (char*)a_s);
  hipMemsetAsync(a_s, 0, zero_bytes, stream);

  detect_dtype<<<1, 256, 0, stream>>>((const u32*)X, flag);
  prep<<<512, 256, 0, stream>>>(W1, W2, atts, attd, W1b, W2b, attsb, attdb,
                                W1T, W2T, flag);

  const int MBG = (N_NODES + 63) / 64;  // 782 (gemm128 M-tiles)

  // h1p = X @ W1^T -> feat (bf16), fused attention dots -> a_s/a_d.
  // Two dtype-specialized variants; each early-exits unless *flag matches.
  // f32 variant fuses X f32->bf16 into A staging; double-buffered 2-phase.
  gemm128<3, 1><<<dim3(MBG, HID / 128), 256, 0, stream>>>(
      (const u16*)X, nullptr, W1b, feat, nullptr, 0, attsb, attdb, a_s, a_d,
      flag, N_NODES, HID, IN_DIM);
  gemm128<3, 0><<<dim3(MBG, HID / 128), 256, 0, stream>>>(
      nullptr, (const float*)X, W1b, feat, nullptr, 0, attsb, attdb, a_s, a_d,
      flag, N_NODES, HID, IN_DIM);

  // CSR by dst + edge weights
  const int NB = (N_NODES + 255) / 256;
  hist_kernel<<<(N_EDGES + 255) / 256, 256, 0, stream>>>(edst, counts);
  block_sum<<<NB, 256, 0, stream>>>(counts, N_NODES, bsums);
  scan_bsums<<<1, 256, 0, stream>>>(bsums, NB, boffs);
  scan_final<<<NB, 256, 0, stream>>>(counts, boffs, N_NODES, offsets, cursor);
  edge_scatter<<<(N_EDGES + 255) / 256, 256, 0, stream>>>(esrc, edst, a_s, a_d,
                                                          denom, cursor, edges);

  // h1 = elu(P . h1p)
  prop256<<<N_NODES / 8, 256, 0, stream>>>(offsets, edges, denom, feat, h1);
  // h2 = h1 @ W2^T -> d_out (dual) + h2b (bf16)
  gemm_h2<<<dim3(MBG, 1), 256, 0, stream>>>(h1, W2b, d_out, h2b, flag,
                                            N_NODES, OUT_DIM, HID);
  // ph2 = P . h2   (64-dim propagate; commutes with @W2 since ELU is outside)
  prop64<<<(N_NODES + 31) / 32, 256, 0, stream>>>(offsets, edges, denom, h2b, ph2);
  // h3 = elu(ph2 @ W2) = elu(P . (h2 @ W2))  -> feat buffer (bf16)
  gemm128<2, 1><<<dim3(MBG, HID / 128), 256, 0, stream>>>(
      ph2, nullptr, W2T, feat, nullptr, 0, nullptr, nullptr, nullptr, nullptr,
      flag, N_NODES, HID, OUT_DIM);
  // h4 = h3 @ W1 -> d_out tail (dual)
  gemm128<1, 1><<<dim3(MBG, IN_DIM / 128), 256, 0, stream>>>(
      feat, nullptr, W1T, nullptr, d_out, (size_t)N_NODES * OUT_DIM,
      nullptr, nullptr, nullptr, nullptr, flag, N_NODES, IN_DIM, HID);
}

// Round 7
// 423.339 us; speedup vs baseline: 1.0345x; 1.0345x over previous
//
#include <hip/hip_runtime.h>
#include <hip/hip_bf16.h>

typedef unsigned short u16;
typedef unsigned int   u32;

#define N_NODES 50000
#define N_EDGES 500000
#define IN_DIM  512
#define HID     256
#define OUT_DIM 64

typedef __bf16 bf16x8 __attribute__((ext_vector_type(8)));
typedef float  f32x4  __attribute__((ext_vector_type(4)));

#define GLOBAL_AS __attribute__((address_space(1)))
#define LDS_AS    __attribute__((address_space(3)))

__device__ __forceinline__ float bf2f(u16 u) {
  union { u32 i; float f; } x; x.i = ((u32)u) << 16; return x.f;
}
__device__ __forceinline__ u16 f2bf(float f) {
  union { float f; u32 i; } x; x.f = f;
  u32 r = x.i + 0x7FFFu + ((x.i >> 16) & 1u);
  return (u16)(r >> 16);
}
__device__ __forceinline__ u32 pkbf(float a, float b) {
  return (u32)f2bf(a) | ((u32)f2bf(b) << 16);
}
__device__ __forceinline__ float lo2f(u32 w) {
  union { u32 i; float f; } x; x.i = w << 16; return x.f;
}
__device__ __forceinline__ float hi2f(u32 w) {
  union { u32 i; float f; } x; x.i = w & 0xFFFF0000u; return x.f;
}

// ---------------- dtype detector (validated R2/R3) ----------------
__global__ void detect_dtype(const u32* __restrict__ feat, int* __restrict__ flag) {
  __shared__ int s[256];
  int t = threadIdx.x;
  int hits = 0;
  for (int i = t; i < 1024; i += 256) {
    u32 e = (feat[i] >> 7) & 0xFF;
    hits += (e >= 100 && e <= 140) ? 1 : 0;
  }
  s[t] = hits;
  __syncthreads();
  for (int o = 128; o > 0; o >>= 1) {
    if (t < o) s[t] += s[t + o];
    __syncthreads();
  }
  if (t == 0) *flag = (s[0] > 716) ? 1 : 0;  // 1 = bf16, 0 = f32
}

// ---------------- one-shot weight/attn prep: convert + transposes ----------
__global__ void prep(const void* __restrict__ W1r, const void* __restrict__ W2r,
                     const void* __restrict__ atsr, const void* __restrict__ atdr,
                     u16* __restrict__ W1b, u16* __restrict__ W2b,
                     u16* __restrict__ attsb, u16* __restrict__ attdb,
                     u16* __restrict__ W1T, u16* __restrict__ W2T,
                     const int* __restrict__ flag) {
  const int fv = *flag;
  int i = blockIdx.x * 256 + threadIdx.x;
  int stride = gridDim.x * 256;
  const int NW1 = HID * IN_DIM;   // 131072
  const int NW2 = OUT_DIM * HID;  // 16384
  for (int j = i; j < NW1; j += stride) {
    u16 v = fv ? ((const u16*)W1r)[j] : f2bf(((const float*)W1r)[j]);
    W1b[j] = v;
    int r = j >> 9, c = j & 511;        // j / IN_DIM, j % IN_DIM
    W1T[c * HID + r] = v;
  }
  for (int j = i; j < NW2; j += stride) {
    u16 v = fv ? ((const u16*)W2r)[j] : f2bf(((const float*)W2r)[j]);
    W2b[j] = v;
    int r = j >> 8, c = j & 255;        // j / HID, j % HID
    W2T[c * OUT_DIM + r] = v;
  }
  if (blockIdx.x == 0 && threadIdx.x < HID) {
    int t = threadIdx.x;
    attsb[t] = fv ? ((const u16*)atsr)[t] : f2bf(((const float*)atsr)[t]);
    attdb[t] = fv ? ((const u16*)atdr)[t] : f2bf(((const float*)atdr)[t]);
  }
}

// ---------------- async 16B global->LDS ----------------
__device__ __forceinline__ void glds16(const u16* g, __bf16* l) {
  __builtin_amdgcn_global_load_lds((const GLOBAL_AS u32*)g, (LDS_AS u32*)l, 16, 0, 0);
}

// ---------------- NT GEMM: C[M,N]=A[M,K]*B[N,K]^T ----------------
// R7: 32x128 tile (shrunk from 64x128; latency-bound, occupancy was 24% ->
// max TLP: grid 1563x{2,4}, LDS 20.5KB -> 8 blocks/CU wave-capped).
// BK=64, 4 waves (2Mx2N: 16x64 each), 8 MFMA/wave/iter. R5 T14 staging:
// A reg-prefetch 1-deep (2 loads/thread), B glds16, counted vmcnt(2)
// (drains 4 B glds16, keeps 2 A loads in flight across the barrier).
// LDS layout: row-major [row][64] bf16 with 16B-segment XOR swizzle
// (phys_seg = seg ^ (row&7)); glds16 pre-swizzles the GLOBAL address
// (m173/G21), reg path swizzles the ds_write address. Reads apply same XOR.
// ABF16=1: A staged via global_load_lds (bf16 input), m97 barrier structure.
// ABF16=0: A is f32; reg-stage + convert fused.
// MODE 1: final out (f32/bf16 per *flag) at outbase+out_off
// MODE 2: bf16 -> Cb with fused ELU
// MODE 3: bf16 -> Cb + fused attention dots (atomicAdd partials to a_s/a_d)
template <int MODE, int ABF16>
__global__ __launch_bounds__(256) void gemm128(const u16* __restrict__ A,
                                               const float* __restrict__ Af32,
                                               const u16* __restrict__ B,
                                               u16* __restrict__ Cb,
                                               void* __restrict__ outbase,
                                               size_t out_off,
                                               const u16* __restrict__ attsb,
                                               const u16* __restrict__ attdb,
                                               float* __restrict__ a_s,
                                               float* __restrict__ a_d,
                                               const int* __restrict__ flag,
                                               int M, int N, int K) {
  __shared__ __bf16 As[32 * 64];
  __shared__ __bf16 Bs[128 * 64];
  __shared__ float as_l[128];
  __shared__ float ad_l[128];

  const int fv = *flag;
  if (MODE == 3 && ABF16 != fv) return;  // dtype-specialized variant gate

  const int tid  = threadIdx.x;
  const int wave = tid >> 6;
  const int lane = tid & 63;
  const int m0   = blockIdx.x * 32;
  const int n0   = blockIdx.y * 128;
  const int wm   = (wave >> 1) * 16;   // 2 waves in M, 16 rows each
  const int wn   = (wave & 1) * 64;    // 2 waves in N, 64 cols each
  const int quad = lane >> 4;
  const int l16  = lane & 15;

  if (MODE == 3 && tid < 128) {
    as_l[tid] = bf2f(attsb[n0 + tid]);
    ad_l[tid] = bf2f(attdb[n0 + tid]);
  }

  // staging geometry: per glds16 round a wave covers 8 rows x 8 segs of 16B
  const int r8 = lane >> 3;        // row within 8-row group
  const int sg = (lane & 7) ^ r8;  // pre-swizzled global 16B segment

  const u16* bp[4];
#pragma unroll
  for (int l = 0; l < 4; ++l) {
    int br = n0 + l * 32 + wave * 8 + r8;  // N is a multiple of 128
    bp[l] = B + (size_t)br * K + sg * 8;
  }

  const u16* ap0 = nullptr;
  if (ABF16) {
    int ar = m0 + wave * 8 + r8;   // 4 waves x 8 rows = 32 rows
    if (ar >= M) ar = M - 1;
    ap0 = A + (size_t)ar * K + sg * 8;
  }
  // f32 reg-stage path: thread t -> row t>>3 (0..31), seg t&7 (8 floats)
  const float* afp = nullptr;
  const int rr = tid >> 3, hh = tid & 7;
  if (!ABF16) {
    int ar = m0 + rr;
    if (ar >= M) ar = M - 1;
    afp = Af32 + (size_t)ar * K + hh * 8;
  }

  f32x4 acc[4];
#pragma unroll
  for (int j = 0; j < 4; ++j) acc[j] = (f32x4)0.f;

  float4 fa[2];
  if (!ABF16) {
    // prologue: prefetch A tile 0 into regs
    fa[0] = *(const float4*)(afp);
    fa[1] = *(const float4*)(afp + 4);
  }

  for (int k0 = 0; k0 < K; k0 += 64) {
    if (ABF16) {
      __syncthreads();
      glds16(ap0 + k0, As + (wave * 8) * 64);
#pragma unroll
      for (int l = 0; l < 4; ++l)
        glds16(bp[l] + k0, Bs + (l * 32 + wave * 8) * 64);
      __syncthreads();
    } else {
      // ---- T14 pipelined staging ----
      __builtin_amdgcn_s_barrier();            // all waves done reading LDS(t-1)
      __builtin_amdgcn_sched_barrier(0);
      // 1) issue B glds16 first (oldest of this phase's vmem ops)
#pragma unroll
      for (int l = 0; l < 4; ++l)
        glds16(bp[l] + k0, Bs + (l * 32 + wave * 8) * 64);
      __builtin_amdgcn_sched_barrier(0);
      // 2) convert prefetched regs (compiler waits the 2 A loads)
      {
        int phys = (hh ^ (rr & 7)) * 8;
        uint4 o;
        o.x = pkbf(fa[0].x, fa[0].y);
        o.y = pkbf(fa[0].z, fa[0].w);
        o.z = pkbf(fa[1].x, fa[1].y);
        o.w = pkbf(fa[1].z, fa[1].w);
        *(uint4*)&As[rr * 64 + phys] = o;
      }
      __builtin_amdgcn_sched_barrier(0);
      // 3) issue A prefetch for tile t+1 (stays in flight across barrier)
      if (k0 + 64 < K) {
        fa[0] = *(const float4*)(afp + k0 + 64);
        fa[1] = *(const float4*)(afp + k0 + 68);
        __builtin_amdgcn_sched_barrier(0);
        // 4) drain glds16 B (4 oldest) + ds_writes; keep 2 A loads in flight
        asm volatile("s_waitcnt vmcnt(2) lgkmcnt(0)" ::: "memory");
      } else {
        asm volatile("s_waitcnt vmcnt(0) lgkmcnt(0)" ::: "memory");
      }
      __builtin_amdgcn_sched_barrier(0);
      __builtin_amdgcn_s_barrier();
      __builtin_amdgcn_sched_barrier(0);
    }

    bf16x8 af[2], bfr[4][2];
#pragma unroll
    for (int ks = 0; ks < 2; ++ks) {
      af[ks] = *(const bf16x8*)&As[(wm + l16) * 64 +
                                   (((ks * 4 + quad) ^ (l16 & 7)) * 8)];
#pragma unroll
      for (int ni = 0; ni < 4; ++ni)
        bfr[ni][ks] = *(const bf16x8*)&Bs[(wn + ni * 16 + l16) * 64 +
                                          (((ks * 4 + quad) ^ (l16 & 7)) * 8)];
    }
#pragma unroll
    for (int ks = 0; ks < 2; ++ks)
#pragma unroll
      for (int ni = 0; ni < 4; ++ni)
        acc[ni] = __builtin_amdgcn_mfma_f32_16x16x32_bf16(
            af[ks], bfr[ni][ks], acc[ni], 0, 0, 0);
  }

  if (MODE == 3) {
    __syncthreads();  // as_l/ad_l visible (loaded pre-loop, barrier-covered anyway)
#pragma unroll
    for (int r = 0; r < 4; ++r) {
      float ps = 0.f, pd = 0.f;
#pragma unroll
      for (int ni = 0; ni < 4; ++ni) {
        int c = wn + ni * 16 + l16;
        ps += acc[ni][r] * as_l[c];
        pd += acc[ni][r] * ad_l[c];
      }
#pragma unroll
      for (int o = 1; o < 16; o <<= 1) {
        ps += __shfl_xor(ps, o);
        pd += __shfl_xor(pd, o);
      }
      int gr = m0 + wm + quad * 4 + r;
      if (l16 == 0 && gr < M) {
        atomicAdd(&a_s[gr], ps);
        atomicAdd(&a_d[gr], pd);
      }
    }
  }

#pragma unroll
  for (int ni = 0; ni < 4; ++ni)
#pragma unroll
    for (int r = 0; r < 4; ++r) {
      int gr = m0 + wm + quad * 4 + r;          // row = quad*4+reg (m89)
      int gc = n0 + wn + ni * 16 + l16;         // col = lane&15
      if (gr < M) {
        float  v   = acc[ni][r];
        size_t idx = (size_t)gr * N + gc;
        if (MODE == 1) {
          if (fv) ((u16*)outbase)[out_off + idx] = f2bf(v);
          else    ((float*)outbase)[out_off + idx] = v;
        } else if (MODE == 2) {
          v = (v > 0.f) ? v : expm1f(v);
          Cb[idx] = f2bf(v);
        } else {
          Cb[idx] = f2bf(v);
        }
      }
    }
}

// ---------------- 64-tile NT GEMM for N=64 (h2): dual out + bf16 copy -----
__global__ __launch_bounds__(256) void gemm_h2(const u16* __restrict__ A,
                                               const u16* __restrict__ B,
                                               void* __restrict__ outbase,
                                               u16* __restrict__ Cb,
                                               const int* __restrict__ flag,
                                               int M, int N, int K) {
  __shared__ __bf16 As[64 * 48];
  __shared__ __bf16 Bs[64 * 48];

  const int tid  = threadIdx.x;
  const int m0   = blockIdx.x * 64;
  const int wave = tid >> 6;
  const int lane = tid & 63;
  const int wm   = (wave >> 1) * 32;
  const int wn   = (wave & 1) * 32;
  const int quad = lane >> 4;
  const int l16  = lane & 15;

  const int srow = tid >> 2;
  const int sseg = (tid & 3) * 8;
  int arow = m0 + srow;
  if (arow >= M) arow = M - 1;
  const size_t a_base = (size_t)arow * K + sseg;
  const size_t b_base = (size_t)srow * K + sseg;  // n0 = 0 (N=64)

  f32x4 acc[2][2];
#pragma unroll
  for (int i = 0; i < 2; ++i)
#pragma unroll
    for (int j = 0; j < 2; ++j) acc[i][j] = (f32x4)0.f;

  for (int k0 = 0; k0 < K; k0 += 32) {
    uint4 av = *(const uint4*)(A + a_base + k0);
    uint4 bv = *(const uint4*)(B + b_base + k0);
    __syncthreads();
    *(uint4*)(&As[srow * 48 + sseg]) = av;
    *(uint4*)(&Bs[srow * 48 + sseg]) = bv;
    __syncthreads();

    bf16x8 af[2], bfr[2];
#pragma unroll
    for (int mi = 0; mi < 2; ++mi)
      af[mi] = *(const bf16x8*)(&As[(wm + mi * 16 + l16) * 48 + quad * 8]);
#pragma unroll
    for (int ni = 0; ni < 2; ++ni)
      bfr[ni] = *(const bf16x8*)(&Bs[(wn + ni * 16 + l16) * 48 + quad * 8]);
#pragma unroll
    for (int mi = 0; mi < 2; ++mi)
#pragma unroll
      for (int ni = 0; ni < 2; ++ni)
        acc[mi][ni] = __builtin_amdgcn_mfma_f32_16x16x32_bf16(
            af[mi], bfr[ni], acc[mi][ni], 0, 0, 0);
  }

  const int fv = *flag;
#pragma unroll
  for (int mi = 0; mi < 2; ++mi)
#pragma unroll
    for (int ni = 0; ni < 2; ++ni)
#pragma unroll
      for (int r = 0; r < 4; ++r) {
        int gr = m0 + wm + mi * 16 + quad * 4 + r;
        int gc = wn + ni * 16 + l16;
        if (gr < M && gc < N) {
          float  v   = acc[mi][ni][r];
          size_t idx = (size_t)gr * N + gc;
          u16 bv = f2bf(v);
          if (fv) ((u16*)outbase)[idx] = bv;
          else    ((float*)outbase)[idx] = v;
          Cb[idx] = bv;
        }
      }
}

// ---------------- CSR build ----------------
__global__ void hist_kernel(const int* __restrict__ dst, int* __restrict__ counts) {
  int e = blockIdx.x * 256 + threadIdx.x;
  if (e < N_EDGES) atomicAdd(&counts[dst[e]], 1);
}

__global__ void block_sum(const int* __restrict__ counts, int n,
                          int* __restrict__ bsums) {
  __shared__ int s[256];
  int i = blockIdx.x * 256 + threadIdx.x;
  s[threadIdx.x] = (i < n) ? counts[i] : 0;
  __syncthreads();
  for (int off = 128; off > 0; off >>= 1) {
    if (threadIdx.x < off) s[threadIdx.x] += s[threadIdx.x + off];
    __syncthreads();
  }
  if (threadIdx.x == 0) bsums[blockIdx.x] = s[0];
}

__global__ void scan_bsums(const int* __restrict__ bsums, int nb,
                           int* __restrict__ boffs) {
  __shared__ int s[256];
  int t = threadIdx.x;
  int v = (t < nb) ? bsums[t] : 0;
  s[t] = v;
  __syncthreads();
  for (int off = 1; off < 256; off <<= 1) {
    int add = (t >= off) ? s[t - off] : 0;
    __syncthreads();
    s[t] += add;
    __syncthreads();
  }
  boffs[t] = s[t] - v;  // exclusive
}

__global__ void scan_final(const int* __restrict__ counts,
                           const int* __restrict__ boffs, int n,
                           int* __restrict__ offsets, int* __restrict__ cursor) {
  __shared__ int s[256];
  int t = threadIdx.x;
  int i = blockIdx.x * 256 + t;
  int v = (i < n) ? counts[i] : 0;
  s[t] = v;
  __syncthreads();
  for (int off = 1; off < 256; off <<= 1) {
    int add = (t >= off) ? s[t - off] : 0;
    __syncthreads();
    s[t] += add;
    __syncthreads();
  }
  int excl = boffs[blockIdx.x] + s[t] - v;
  if (i < n) {
    offsets[i] = excl;
    cursor[i]  = excl;
  }
  if (i == n - 1) offsets[n] = excl + v;
}

// sigmoid in (0,1) -> exp never overflows; segment-max cancels in softmax.
__global__ void edge_scatter(const int* __restrict__ src, const int* __restrict__ dst,
                             const float* __restrict__ a_s, const float* __restrict__ a_d,
                             float* __restrict__ denom, int* __restrict__ cursor,
                             int2* __restrict__ edges) {
  int e = blockIdx.x * 256 + threadIdx.x;
  if (e >= N_EDGES) return;
  int s = src[e], d = dst[e];
  float x  = a_s[s] + a_d[d];
  float a  = 1.f / (1.f + expf(-x));
  float ev = expf(a);
  atomicAdd(&denom[d], ev);
  int pos = atomicAdd(&cursor[d], 1);
  edges[pos] = make_int2(s, __float_as_int(ev));
}

// ---------------- prop 256-dim: 32-lane subgroup/node, fused ELU ----------
// Edge loop unrolled x2: two (edge, row) load pairs in flight per iteration
// (hipcc otherwise drains vmcnt before each row use -> 1 gather in flight).
__global__ __launch_bounds__(256) void prop256(
    const int* __restrict__ offs, const int2* __restrict__ edges,
    const float* __restrict__ denom, const u16* __restrict__ feat,
    u16* __restrict__ out) {
  const int sub  = threadIdx.x >> 5;
  const int lane = threadIdx.x & 31;
  const int nd   = blockIdx.x * 8 + sub;
  const int col  = lane * 8;
  const int beg = offs[nd], end = offs[nd + 1];
  float a[8];
#pragma unroll
  for (int j = 0; j < 8; ++j) a[j] = 0.f;
  int e = beg;
  for (; e + 1 < end; e += 2) {
    int2  e0 = edges[e];
    int2  e1 = edges[e + 1];
    float v0 = __int_as_float(e0.y);
    float v1 = __int_as_float(e1.y);
    uint4 w0 = *(const uint4*)(feat + (size_t)e0.x * HID + col);
    uint4 w1 = *(const uint4*)(feat + (size_t)e1.x * HID + col);
    a[0] += v0 * lo2f(w0.x); a[1] += v0 * hi2f(w0.x);
    a[2] += v0 * lo2f(w0.y); a[3] += v0 * hi2f(w0.y);
    a[4] += v0 * lo2f(w0.z); a[5] += v0 * hi2f(w0.z);
    a[6] += v0 * lo2f(w0.w); a[7] += v0 * hi2f(w0.w);
    a[0] += v1 * lo2f(w1.x); a[1] += v1 * hi2f(w1.x);
    a[2] += v1 * lo2f(w1.y); a[3] += v1 * hi2f(w1.y);
    a[4] += v1 * lo2f(w1.z); a[5] += v1 * hi2f(w1.z);
    a[6] += v1 * lo2f(w1.w); a[7] += v1 * hi2f(w1.w);
  }
  if (e < end) {
    int2  ed = edges[e];
    float ev = __int_as_float(ed.y);
    uint4 w = *(const uint4*)(feat + (size_t)ed.x * HID + col);
    a[0] += ev * lo2f(w.x); a[1] += ev * hi2f(w.x);
    a[2] += ev * lo2f(w.y); a[3] += ev * hi2f(w.y);
    a[4] += ev * lo2f(w.z); a[5] += ev * hi2f(w.z);
    a[6] += ev * lo2f(w.w); a[7] += ev * hi2f(w.w);
  }
  float dn = 1.f / (denom[nd] + 1e-16f);
  u32 p[4];
#pragma unroll
  for (int j = 0; j < 4; ++j) {
    float r0 = a[2 * j] * dn;
    float r1 = a[2 * j + 1] * dn;
    r0 = (r0 > 0.f) ? r0 : expm1f(r0);
    r1 = (r1 > 0.f) ? r1 : expm1f(r1);
    p[j] = (u32)f2bf(r0) | ((u32)f2bf(r1) << 16);
  }
  *(uint4*)(out + (size_t)nd * HID + col) = make_uint4(p[0], p[1], p[2], p[3]);
}

// ---------------- prop 64-dim (on h2): 8-lane subgroup/node, no ELU -------
__global__ __launch_bounds__(256) void prop64(
    const int* __restrict__ offs, const int2* __restrict__ edges,
    const float* __restrict__ denom, const u16* __restrict__ feat,
    u16* __restrict__ out) {
  const int sub  = threadIdx.x >> 3;
  const int lane = threadIdx.x & 7;
  const int nd   = blockIdx.x * 32 + sub;
  if (nd >= N_NODES) return;
  const int col  = lane * 8;
  const int beg = offs[nd], end = offs[nd + 1];
  float a[8];
#pragma unroll
  for (int j = 0; j < 8; ++j) a[j] = 0.f;
  int e = beg;
  for (; e + 1 < end; e += 2) {
    int2  e0 = edges[e];
    int2  e1 = edges[e + 1];
    float v0 = __int_as_float(e0.y);
    float v1 = __int_as_float(e1.y);
    uint4 w0 = *(const uint4*)(feat + (size_t)e0.x * OUT_DIM + col);
    uint4 w1 = *(const uint4*)(feat + (size_t)e1.x * OUT_DIM + col);
    a[0] += v0 * lo2f(w0.x); a[1] += v0 * hi2f(w0.x);
    a[2] += v0 * lo2f(w0.y); a[3] += v0 * hi2f(w0.y);
    a[4] += v0 * lo2f(w0.z); a[5] += v0 * hi2f(w0.z);
    a[6] += v0 * lo2f(w0.w); a[7] += v0 * hi2f(w0.w);
    a[0] += v1 * lo2f(w1.x); a[1] += v1 * hi2f(w1.x);
    a[2] += v1 * lo2f(w1.y); a[3] += v1 * hi2f(w1.y);
    a[4] += v1 * lo2f(w1.z); a[5] += v1 * hi2f(w1.z);
    a[6] += v1 * lo2f(w1.w); a[7] += v1 * hi2f(w1.w);
  }
  if (e < end) {
    int2  ed = edges[e];
    float ev = __int_as_float(ed.y);
    uint4 w = *(const uint4*)(feat + (size_t)ed.x * OUT_DIM + col);
    a[0] += ev * lo2f(w.x); a[1] += ev * hi2f(w.x);
    a[2] += ev * lo2f(w.y); a[3] += ev * hi2f(w.y);
    a[4] += ev * lo2f(w.z); a[5] += ev * hi2f(w.z);
    a[6] += ev * lo2f(w.w); a[7] += ev * hi2f(w.w);
  }
  float dn = 1.f / (denom[nd] + 1e-16f);
  u32 p[4];
#pragma unroll
  for (int j = 0; j < 4; ++j) {
    p[j] = (u32)f2bf(a[2 * j] * dn) | ((u32)f2bf(a[2 * j + 1] * dn) << 16);
  }
  *(uint4*)(out + (size_t)nd * OUT_DIM + col) = make_uint4(p[0], p[1], p[2], p[3]);
}

// ---------------- launch ----------------
extern "C" void kernel_launch(void* const* d_in, const int* in_sizes, int n_in,
                              void* d_out, int out_size, void* d_ws, size_t ws_size,
                              hipStream_t stream) {
  const void* X    = d_in[0];
  const void* W1   = d_in[1];
  const void* W2   = d_in[2];
  const void* atts = d_in[3];
  const void* attd = d_in[4];
  const int*  eidx = (const int*)d_in[5];
  const int*  esrc = eidx;
  const int*  edst = eidx + N_EDGES;

  char*  ws  = (char*)d_ws;
  size_t off = 0;
  auto alloc = [&](size_t bytes) -> void* {
    void* p = ws + off;
    off += (bytes + 255) & ~(size_t)255;
    return p;
  };
  u16*   W1b    = (u16*)alloc((size_t)HID * IN_DIM * 2);
  u16*   W2b    = (u16*)alloc((size_t)OUT_DIM * HID * 2);
  u16*   attsb  = (u16*)alloc(HID * 2);
  u16*   attdb  = (u16*)alloc(HID * 2);
  u16*   W1T    = (u16*)alloc((size_t)IN_DIM * HID * 2);
  u16*   W2T    = (u16*)alloc((size_t)HID * OUT_DIM * 2);
  u16*   feat   = (u16*)alloc((size_t)N_NODES * HID * 2);   // h1p, later h3
  u16*   h1     = (u16*)alloc((size_t)N_NODES * HID * 2);
  u16*   h2b    = (u16*)alloc((size_t)N_NODES * OUT_DIM * 2);
  u16*   ph2    = (u16*)alloc((size_t)N_NODES * OUT_DIM * 2);
  float* a_s    = (float*)alloc(N_NODES * 4);   // zero region start
  float* a_d    = (float*)alloc(N_NODES * 4);
  float* denom  = (float*)alloc(N_NODES * 4);
  int*   counts = (int*)alloc(N_NODES * 4);     // zero region end
  int*   offsets= (int*)alloc((N_NODES + 1) * 4);
  int*   cursor = (int*)alloc(N_NODES * 4);
  int*   bsums  = (int*)alloc(1024 * 4);
  int*   boffs  = (int*)alloc(1024 * 4);
  int2*  edges  = (int2*)alloc((size_t)N_EDGES * 8);
  int*   flag   = (int*)alloc(256);
  (void)ws_size; (void)in_sizes; (void)n_in; (void)out_size;

  size_t zero_bytes = (size_t)((char*)offsets - (char*)a_s);
  hipMemsetAsync(a_s, 0, zero_bytes, stream);

  detect_dtype<<<1, 256, 0, stream>>>((const u32*)X, flag);
  prep<<<512, 256, 0, stream>>>(W1, W2, atts, attd, W1b, W2b, attsb, attdb,
                                W1T, W2T, flag);

  const int MB32 = (N_NODES + 31) / 32;  // 1563 (gemm128 M-tiles)
  const int MB64 = (N_NODES + 63) / 64;  // 782  (gemm_h2)

  // h1p = X @ W1^T -> feat (bf16), fused attention dots -> a_s/a_d.
  // Two dtype-specialized variants; each early-exits unless *flag matches.
  // f32 variant fuses X f32->bf16 into A staging (old cvt8 pass removed),
  // T14-pipelined (prefetch regs stay in flight across barriers).
  gemm128<3, 1><<<dim3(MB32, HID / 128), 256, 0, stream>>>(
      (const u16*)X, nullptr, W1b, feat, nullptr, 0, attsb, attdb, a_s, a_d,
      flag, N_NODES, HID, IN_DIM);
  gemm128<3, 0><<<dim3(MB32, HID / 128), 256, 0, stream>>>(
      nullptr, (const float*)X, W1b, feat, nullptr, 0, attsb, attdb, a_s, a_d,
      flag, N_NODES, HID, IN_DIM);

  // CSR by dst + edge weights
  const int NB = (N_NODES + 255) / 256;
  hist_kernel<<<(N_EDGES + 255) / 256, 256, 0, stream>>>(edst, counts);
  block_sum<<<NB, 256, 0, stream>>>(counts, N_NODES, bsums);
  scan_bsums<<<1, 256, 0, stream>>>(bsums, NB, boffs);
  scan_final<<<NB, 256, 0, stream>>>(counts, boffs, N_NODES, offsets, cursor);
  edge_scatter<<<(N_EDGES + 255) / 256, 256, 0, stream>>>(esrc, edst, a_s, a_d,
                                                          denom, cursor, edges);

  // h1 = elu(P . h1p)
  prop256<<<N_NODES / 8, 256, 0, stream>>>(offsets, edges, denom, feat, h1);
  // h2 = h1 @ W2^T -> d_out (dual) + h2b (bf16)
  gemm_h2<<<dim3(MB64, 1), 256, 0, stream>>>(h1, W2b, d_out, h2b, flag,
                                             N_NODES, OUT_DIM, HID);
  // ph2 = P . h2   (64-dim propagate; commutes with @W2 since ELU is outside)
  prop64<<<(N_NODES + 31) / 32, 256, 0, stream>>>(offsets, edges, denom, h2b, ph2);
  // h3 = elu(ph2 @ W2) = elu(P . (h2 @ W2))  -> feat buffer (bf16)
  gemm128<2, 1><<<dim3(MB32, HID / 128), 256, 0, stream>>>(
      ph2, nullptr, W2T, feat, nullptr, 0, nullptr, nullptr, nullptr, nullptr,
      flag, N_NODES, HID, OUT_DIM);
  // h4 = h3 @ W1 -> d_out tail (dual)
  gemm128<1, 1><<<dim3(MB32, IN_DIM / 128), 256, 0, stream>>>(
      feat, nullptr, W1T, nullptr, d_out, (size_t)N_NODES * OUT_DIM,
      nullptr, nullptr, nullptr, nullptr, flag, N_NODES, IN_DIM, HID);
}